// Round 3
// baseline (879.015 us; speedup 1.0000x reference)
//
#include <hip/hip_runtime.h>
#include <cstdint>
#include <cstddef>

#define TSTEPS 1024
#define NB 256
#define NI 128
#define NH 128
#define NC 18
#define CH 32
#define NCHUNK (TSTEPS/CH)   // 32
#define XGS 516              // xgp row stride in f32

#define LOG2E_F    1.44269504088896f
#define TWO_LOG2E_F 2.88539008177793f

typedef _Float16 f16x8 __attribute__((ext_vector_type(8)));
typedef float    f32x4 __attribute__((ext_vector_type(4)));
typedef _Float16 half2_t __attribute__((ext_vector_type(2)));

__device__ __forceinline__ half2_t as_h2(uint32_t v){
  union { uint32_t u; half2_t h; } cv; cv.u = v; return cv.h;
}
__device__ __forceinline__ uint32_t pku(float a, float b){
  union { half2_t h; uint32_t u; } cv; cv.h.x=(_Float16)a; cv.h.y=(_Float16)b; return cv.u;
}
__device__ __forceinline__ float dot2f(half2_t a, half2_t b, float c){
#if __has_builtin(__builtin_amdgcn_fdot2)
  return __builtin_amdgcn_fdot2(a, b, c, false);
#else
  return c + (float)a.x*(float)b.x + (float)a.y*(float)b.y;
#endif
}
__device__ __forceinline__ float fast_rcp(float x){
#if __has_builtin(__builtin_amdgcn_rcpf)
  return __builtin_amdgcn_rcpf(x);
#else
  return 1.f / x;
#endif
}
__device__ __forceinline__ float exp2x(float v){
#if __has_builtin(__builtin_amdgcn_exp2f)
  return __builtin_amdgcn_exp2f(v);
#else
  return __expf(v * 0.6931471805599453f);
#endif
}
// sigmoid with pre-scaled input vp = v*log2e
__device__ __forceinline__ float sigm2(float vp){
  return fast_rcp(1.f + exp2x(-vp));
}
// tanh with pre-scaled input vp = 2*log2e*v : tanh(v) = 1 - 2/(1+2^vp)
__device__ __forceinline__ float tanh2p(float vp){
  return __builtin_fmaf(-2.f, fast_rcp(1.f + exp2x(vp)), 1.f);
}
// 8 consecutive f32 -> f16x8 with scale
__device__ __forceinline__ f16x8 ldrow_f16s(const float* base, float s){
  float4 f0 = ((const float4*)base)[0];
  float4 f1 = ((const float4*)base)[1];
  f16x8 r;
  r[0]=(_Float16)(f0.x*s); r[1]=(_Float16)(f0.y*s); r[2]=(_Float16)(f0.z*s); r[3]=(_Float16)(f0.w*s);
  r[4]=(_Float16)(f1.x*s); r[5]=(_Float16)(f1.y*s); r[6]=(_Float16)(f1.z*s); r[7]=(_Float16)(f1.w*s);
  return r;
}
// lgkm-only workgroup barrier (global loads/stores stay in flight)
__device__ __forceinline__ void barrier_lds(){
  asm volatile("s_waitcnt lgkmcnt(0)" ::: "memory");
  __builtin_amdgcn_s_barrier();
}

// H-wave x-GEMM tile: compile-time CT (register-array index), runtime MT (addresses only)
#define H_GEMM_TILE(CT, MT_, XGN) do {                                             \
    const _Float16* xr_ = &xs[(MT_)*16 + n][0];                                    \
    f16x8 xa0_ = *(const f16x8*)&xr_[ 0 + quad*8];                                 \
    f16x8 xa1_ = *(const f16x8*)&xr_[32 + quad*8];                                 \
    f16x8 xa2_ = *(const f16x8*)&xr_[64 + quad*8];                                 \
    f16x8 xa3_ = *(const f16x8*)&xr_[96 + quad*8];                                 \
    f32x4 acc_ = { biash[CT], biash[CT], biash[CT], biash[CT] };                   \
    acc_ = __builtin_amdgcn_mfma_f32_16x16x32_f16(xa0_, wfr[CT][0], acc_, 0,0,0);  \
    acc_ = __builtin_amdgcn_mfma_f32_16x16x32_f16(xa1_, wfr[CT][1], acc_, 0,0,0);  \
    acc_ = __builtin_amdgcn_mfma_f32_16x16x32_f16(xa2_, wfr[CT][2], acc_, 0,0,0);  \
    acc_ = __builtin_amdgcn_mfma_f32_16x16x32_f16(xa3_, wfr[CT][3], acc_, 0,0,0);  \
    float* xw_ = &(XGN)[(MT_)*16 + quad*4][((CT)*16 + n)*4 + hq];                  \
    xw_[0] = acc_[0]; xw_[XGS] = acc_[1]; xw_[2*XGS] = acc_[2]; xw_[3*XGS] = acc_[3]; \
  } while(0)

// H-thread xs staging write (one float4 -> 4 f16), M_ literal
#define STAGE_W(M_, XPV) do {                                                      \
    union { _Float16 h_[4]; uint2 u_; } pk_;                                       \
    pk_.h_[0]=(_Float16)(XPV).x; pk_.h_[1]=(_Float16)(XPV).y;                      \
    pk_.h_[2]=(_Float16)(XPV).z; pk_.h_[3]=(_Float16)(XPV).w;                      \
    *(uint2*)&xs[hrW][4*(k8 + 8*(M_))] = pk_.u_;                                   \
  } while(0)

// H-thread head dot: one full 128-wide dot for output (row=hrW of chunk CKH, col=JV)
#define HEAD_DOT(JV, CKH, FB) do {                                                 \
    const int row_ = (((CKH)*CH + hrW) & 63);                                      \
    const uint4* hb_ = (const uint4*)&hist[row_][0];                               \
    const int hx4_ = row_ & 7;                                                     \
    const uint2* fw_ = (const uint2*)&fcw[(JV)][0];                                \
    float a0_=0.f, a1_=0.f, a2_=0.f, a3_=0.f;                                      \
    _Pragma("unroll")                                                              \
    for (int k_ = 0; k_ < 16; ++k_){                                               \
      uint4 v_ = hb_[k_ ^ hx4_];                                                   \
      uint2 fa_ = fw_[2*k_], fb2_ = fw_[2*k_+1];                                   \
      a0_ = dot2f(as_h2(fa_.x),  as_h2(v_.x), a0_);                                \
      a1_ = dot2f(as_h2(fa_.y),  as_h2(v_.y), a1_);                                \
      a2_ = dot2f(as_h2(fb2_.x), as_h2(v_.z), a2_);                                \
      a3_ = dot2f(as_h2(fb2_.y), as_h2(v_.w), a3_);                                \
    }                                                                              \
    out[(size_t)((CKH)*CH + hrW)*NB*NC + (size_t)b*NC + (JV)] =                    \
        (a0_+a1_) + (a2_+a3_) + (FB);                                              \
  } while(0)

// One block per batch row, 512 threads (8 waves), wave-specialized:
//   waves 0-3 (R): recurrence only. Wave w owns cells [w*32, w*32+32): 8 N-tiles x 4 K
//     = 32 MFMA/step. All A-rows are h-replicas -> every lane holds valid gates;
//     quad 0 lanes activate cell w*32+n, quad 2 lanes activate w*32+16+n.
//   waves 4-7 (H): x-GEMM for chunk ck+1, head for chunk ck-1, x stage/prefetch —
//     executed as per-step slices in PARALLEL waves (never on the R critical path).
// wfr[8][4] register file is role-unioned: Whh frags for R, Wih frags for H.
// hist = 64-row ring, XOR-swizzled (elem ^= (row&7)<<3) for conflict-free head reads.
// Weights/bias pre-scaled by log2e (2*log2e for g-gate) -> exp2-native activations.
__global__ __launch_bounds__(512, 2) void lstm_mfma(
    const float* __restrict__ x,      // [T,B,I]
    const float* __restrict__ h0,     // [B,H]
    const float* __restrict__ c0,     // [B,H]
    const float* __restrict__ Wih,    // [4H,I]
    const float* __restrict__ Whh,    // [4H,H]
    const float* __restrict__ bih,    // [4H]
    const float* __restrict__ bhh,    // [4H]
    const float* __restrict__ fcW,    // [18,H]
    const float* __restrict__ fcb,    // [18]
    float* __restrict__ out,          // [T,B,18]
    float* __restrict__ hT,           // [B,H]
    float* __restrict__ cT)           // [B,H]
{
  const int b    = blockIdx.x;
  const int tid  = threadIdx.x;
  const int w    = tid >> 6;        // wave 0..7
  const int l    = tid & 63;
  const int n    = l & 15;
  const int quad = l >> 4;
  const bool isR = (w < 4);
  const bool hi  = (l >= 32);       // R: which cell-subtile this lane activates

  __shared__ __align__(16) _Float16 xs[CH][136];       // x chunk f16 (+pad)    8704 B
  __shared__ __align__(16) float    xgp[2][CH][XGS];   // x-gates dbuf        132096 B
  __shared__ __align__(16) _Float16 hist[64][128];     // h ring (swizzled)    16384 B
  __shared__ __align__(16) uint32_t fcw[NC][66];       // head W f16 (+pad)     4752 B

  // ---- H-role indices ----
  const int hq   = w - 4;            // gate type handled by this H wave
  const int tid2 = hq*64 + l;        // 0..255 (H only)
  const int hrW  = tid2 >> 3;        // time row 0..31 (H only)
  const int k8   = tid2 & 7;
  const int jb   = k8;

  // ---- x chunk-0 prefetch (H only), issued first to hide latency ----
  float4 xp0, xp1, xp2, xp3;
  if (!isR){
    const float* xb = x + ((size_t)hrW*NB + b)*NI;
    xp0 = ((const float4*)xb)[k8];
    xp1 = ((const float4*)xb)[k8+8];
    xp2 = ((const float4*)xb)[k8+16];
    xp3 = ((const float4*)xb)[k8+24];
  }

  // ---- role-unioned persistent weight frags (128 VGPRs) ----
  f16x8 wfr[8][4];
  float biash[8];                     // used by H only (R bias enters via xg)
  {
    const float* wsrc = isR ? Whh : Wih;
#pragma unroll
    for (int f = 0; f < 8; ++f){
      const int g  = isR ? ((f>>1)*128 + w*32 + (f&1)*16 + n)
                         : (hq*128 + f*16 + n);
      const int qq = isR ? (f>>1) : hq;
      const float sc = (qq == 2) ? TWO_LOG2E_F : LOG2E_F;
#pragma unroll
      for (int kt = 0; kt < 4; ++kt)
        wfr[f][kt] = ldrow_f16s(wsrc + (size_t)g*128 + kt*32 + quad*8, sc);
      biash[f] = (bih[g] + bhh[g]) * sc;
    }
  }

  // ---- per-lane cell state (R) ----
  const int mycell = (isR ? w*32 : 0) + (hi ? 16 : 0) + n;
  float cst = 0.f;
  if (isR) cst = c0[(size_t)b*NH + mycell];
  float hlast = 0.f;

  // ---- LDS init: h ring seed (swizzled), head weights ----
  if (tid < 128) hist[63][tid ^ 56] = (_Float16)h0[(size_t)b*NH + tid];
#pragma unroll
  for (int r = 0; r < 3; ++r){
    int idx = tid + 512*r;            // 18*64 = 1152 targets
    if (idx < NC*64){
      int j = idx >> 6, k = idx & 63;
      float2 f = ((const float2*)(fcW + (size_t)j*NH))[k];
      fcw[j][k] = pku(f.x, f.y);
    }
  }
  float fj0 = 0.f, fj1 = 0.f, fj2 = 0.f;
  if (!isR){ fj0 = fcb[jb]; fj1 = fcb[jb+8]; if (jb < 2) fj2 = fcb[16+jb]; }

  // ---- prologue: stage xs(0) ----
  if (!isR){ STAGE_W(0, xp0); STAGE_W(1, xp1); STAGE_W(2, xp2); STAGE_W(3, xp3); }
  barrier_lds();

  // ---- prologue: full x-GEMM(0) -> xgp[0] (H waves), R waves wait ----
  if (!isR){
    float (*xgn)[XGS] = xgp[0];
#pragma unroll
    for (int ct = 0; ct < 8; ++ct)
#pragma unroll
      for (int mt = 0; mt < 2; ++mt)
        H_GEMM_TILE(ct, mt, xgn);
    // prefetch x chunk 1
    const float* xb = x + ((size_t)(CH + hrW)*NB + b)*NI;
    xp0 = ((const float4*)xb)[k8];
    xp1 = ((const float4*)xb)[k8+8];
    xp2 = ((const float4*)xb)[k8+16];
    xp3 = ((const float4*)xb)[k8+24];
  }
  barrier_lds();

  // ================= main loop =================
#pragma unroll 1
  for (int ck = 0; ck < NCHUNK; ++ck){
    float (*xgc)[XGS] = xgp[ck & 1];
    float (*xgn)[XGS] = xgp[(ck + 1) & 1];
    const int tbase = (ck*CH) & 63;

#pragma unroll 4
    for (int tt = 0; tt < CH; ++tt){
      if (isR){
        // ---------- recurrent step ----------
        const int rrow = (tbase + tt + 63) & 63;
        const int hx = (rrow & 7) << 3;
        const _Float16* hp = &hist[rrow][0];
        f16x8 a0 = *(const f16x8*)&hp[( 0 + quad*8) ^ hx];
        f16x8 a1 = *(const f16x8*)&hp[(32 + quad*8) ^ hx];
        f16x8 a2 = *(const f16x8*)&hp[(64 + quad*8) ^ hx];
        f16x8 a3 = *(const f16x8*)&hp[(96 + quad*8) ^ hx];
        const int cb4 = (w*32 + n)*4;
        f32x4 sgA = *(const f32x4*)&xgc[tt][cb4];
        f32x4 sgB = *(const f32x4*)&xgc[tt][cb4 + 64];
        float gA[4], gB[4];
        __builtin_amdgcn_s_setprio(1);
#pragma unroll
        for (int q = 0; q < 4; ++q){
          f32x4 aA; aA[0] = sgA[q];
          aA = __builtin_amdgcn_mfma_f32_16x16x32_f16(a0, wfr[q*2+0][0], aA, 0,0,0);
          aA = __builtin_amdgcn_mfma_f32_16x16x32_f16(a1, wfr[q*2+0][1], aA, 0,0,0);
          f32x4 aB; aB[0] = 0.f;
          aB = __builtin_amdgcn_mfma_f32_16x16x32_f16(a2, wfr[q*2+0][2], aB, 0,0,0);
          aB = __builtin_amdgcn_mfma_f32_16x16x32_f16(a3, wfr[q*2+0][3], aB, 0,0,0);
          gA[q] = aA[0] + aB[0];
        }
#pragma unroll
        for (int q = 0; q < 4; ++q){
          f32x4 aA; aA[0] = sgB[q];
          aA = __builtin_amdgcn_mfma_f32_16x16x32_f16(a0, wfr[q*2+1][0], aA, 0,0,0);
          aA = __builtin_amdgcn_mfma_f32_16x16x32_f16(a1, wfr[q*2+1][1], aA, 0,0,0);
          f32x4 aB; aB[0] = 0.f;
          aB = __builtin_amdgcn_mfma_f32_16x16x32_f16(a2, wfr[q*2+1][2], aB, 0,0,0);
          aB = __builtin_amdgcn_mfma_f32_16x16x32_f16(a3, wfr[q*2+1][3], aB, 0,0,0);
          gB[q] = aA[0] + aB[0];
        }
        __builtin_amdgcn_s_setprio(0);
        // quad-split activation: quads 0/1 -> sub0 cell, quads 2/3 -> sub1 cell
        float gi = hi ? gB[0] : gA[0];
        float gf = hi ? gB[1] : gA[1];
        float gg = hi ? gB[2] : gA[2];
        float go = hi ? gB[3] : gA[3];
        float iv = sigm2(gi);
        float fv = sigm2(gf);
        float gv = tanh2p(gg);               // gg pre-scaled by 2*log2e via weights
        float ov = sigm2(go);
        cst = __builtin_fmaf(fv, cst, iv*gv);
        float hv = ov * tanh2p(cst * TWO_LOG2E_F);
        hlast = hv;
        const int wrow = (tbase + tt) & 63;
        if ((l & 31) < 16)                   // lanes 0-15 and 32-47 write their cell
          hist[wrow][mycell ^ ((wrow & 7) << 3)] = (_Float16)hv;
      } else {
        // ---------- H slices (parallel waves, off the R critical path) ----------
        if (tt == 0){
          if (ck <= NCHUNK-2){ STAGE_W(0, xp0); STAGE_W(1, xp1); }
        } else if (tt == 1){
          if (ck <= NCHUNK-2){ STAGE_W(2, xp2); STAGE_W(3, xp3); }
        } else if (tt == 3){
          if (ck <= NCHUNK-3){
            const float* xb = x + ((size_t)((ck+2)*CH + hrW)*NB + b)*NI;
            xp0 = ((const float4*)xb)[k8];
            xp1 = ((const float4*)xb)[k8+8];
            xp2 = ((const float4*)xb)[k8+16];
            xp3 = ((const float4*)xb)[k8+24];
          }
        } else if (tt >= 4 && tt < 20){
          if (ck <= NCHUNK-2){
            const int slice_ = tt - 4;       // 0..15
            const int mt_ = slice_ & 1;
            switch (slice_ >> 1){
              case 0: H_GEMM_TILE(0, mt_, xgn); break;
              case 1: H_GEMM_TILE(1, mt_, xgn); break;
              case 2: H_GEMM_TILE(2, mt_, xgn); break;
              case 3: H_GEMM_TILE(3, mt_, xgn); break;
              case 4: H_GEMM_TILE(4, mt_, xgn); break;
              case 5: H_GEMM_TILE(5, mt_, xgn); break;
              case 6: H_GEMM_TILE(6, mt_, xgn); break;
              case 7: H_GEMM_TILE(7, mt_, xgn); break;
            }
          }
        } else if (tt == 20){
          if (ck >= 1) HEAD_DOT(jb, ck-1, fj0);
        } else if (tt == 21){
          if (ck >= 1) HEAD_DOT(jb+8, ck-1, fj1);
        } else if (tt == 22){
          if (ck >= 1 && jb < 2) HEAD_DOT(16+jb, ck-1, fj2);
        }
      }
      barrier_lds();
    }
  }

  // ================= epilogue =================
  if (isR){
    if ((l & 31) < 16){
      hT[(size_t)b*NH + mycell] = hlast;
      cT[(size_t)b*NH + mycell] = cst;
    }
  } else {
    // head for chunk 31 (ring rows 32..63), no barriers needed
    HEAD_DOT(jb, NCHUNK-1, fj0);
    HEAD_DOT(jb+8, NCHUNK-1, fj1);
    if (jb < 2) HEAD_DOT(16+jb, NCHUNK-1, fj2);
  }
}

extern "C" void kernel_launch(void* const* d_in, const int* in_sizes, int n_in,
                              void* d_out, int out_size, void* d_ws, size_t ws_size,
                              hipStream_t stream) {
  (void)in_sizes; (void)n_in; (void)d_ws; (void)ws_size; (void)out_size;
  const float* x   = (const float*)d_in[0];
  const float* h0  = (const float*)d_in[1];
  const float* c0  = (const float*)d_in[2];
  const float* Wih = (const float*)d_in[3];
  const float* Whh = (const float*)d_in[4];
  const float* bih = (const float*)d_in[5];
  const float* bhh = (const float*)d_in[6];
  const float* fcW = (const float*)d_in[7];
  const float* fcb = (const float*)d_in[8];
  float* out = (float*)d_out;
  float* hT  = out + (size_t)TSTEPS*NB*NC;   // 4,718,592
  float* cT  = hT + (size_t)NB*NH;           // +32,768
  hipLaunchKernelGGL(lstm_mfma, dim3(NB), dim3(512), 0, stream,
                     x, h0, c0, Wih, Whh, bih, bhh, fcW, fcb, out, hT, cT);
}

// Round 4
// 723.372 us; speedup vs baseline: 1.2152x; 1.2152x over previous
//
#include <hip/hip_runtime.h>
#include <cstdint>
#include <cstddef>

#define TSTEPS 1024
#define NB 256
#define NI 128
#define NH 128
#define NC 18
#define CH 32
#define NCHUNK (TSTEPS/CH)   // 32
#define XGS 516              // xgp row stride in f32

#define LOG2E_F     1.44269504088896f
#define TWO_LOG2E_F 2.88539008177793f

typedef _Float16 f16x8 __attribute__((ext_vector_type(8)));
typedef float    f32x4 __attribute__((ext_vector_type(4)));
typedef _Float16 half2_t __attribute__((ext_vector_type(2)));

__device__ __forceinline__ half2_t as_h2(uint32_t v){
  union { uint32_t u; half2_t h; } cv; cv.u = v; return cv.h;
}
__device__ __forceinline__ uint32_t pku(float a, float b){
  union { half2_t h; uint32_t u; } cv; cv.h.x=(_Float16)a; cv.h.y=(_Float16)b; return cv.u;
}
__device__ __forceinline__ float dot2f(half2_t a, half2_t b, float c){
#if __has_builtin(__builtin_amdgcn_fdot2)
  return __builtin_amdgcn_fdot2(a, b, c, false);
#else
  return c + (float)a.x*(float)b.x + (float)a.y*(float)b.y;
#endif
}
__device__ __forceinline__ float fast_rcp(float x){
#if __has_builtin(__builtin_amdgcn_rcpf)
  return __builtin_amdgcn_rcpf(x);
#else
  return 1.f / x;
#endif
}
__device__ __forceinline__ float exp2x(float v){
#if __has_builtin(__builtin_amdgcn_exp2f)
  return __builtin_amdgcn_exp2f(v);
#else
  return __expf(v * 0.6931471805599453f);
#endif
}
// quad-broadcast via DPP: CTRL = k*0x55 broadcasts lane k of each 4-lane group
template<int CTRL>
__device__ __forceinline__ float qbcast(float v){
#if __has_builtin(__builtin_amdgcn_mov_dpp)
  union { float f; int i; } u; u.f = v;
  u.i = __builtin_amdgcn_mov_dpp(u.i, CTRL, 0xF, 0xF, false);
  return u.f;
#else
  return __shfl(v, ((threadIdx.x & 63) & ~3) + (CTRL & 3), 64);
#endif
}
// 8 consecutive f32 -> f16x8 with scale (one MFMA operand row-slice)
__device__ __forceinline__ f16x8 ldrow_f16s(const float* base, float s){
  float4 f0 = ((const float4*)base)[0];
  float4 f1 = ((const float4*)base)[1];
  f16x8 r;
  r[0]=(_Float16)(f0.x*s); r[1]=(_Float16)(f0.y*s); r[2]=(_Float16)(f0.z*s); r[3]=(_Float16)(f0.w*s);
  r[4]=(_Float16)(f1.x*s); r[5]=(_Float16)(f1.y*s); r[6]=(_Float16)(f1.z*s); r[7]=(_Float16)(f1.w*s);
  return r;
}
// lgkm-only workgroup barrier: all in-loop cross-wave deps are LDS; global
// prefetch loads and out-stores stay in flight across it.
__device__ __forceinline__ void barrier_lds(){
  asm volatile("s_waitcnt lgkmcnt(0)" ::: "memory");
  __builtin_amdgcn_s_barrier();
}

// One block per batch row, 512 threads (8 waves), all uniform (r1 structure).
// Recurrent MFMA col map: B col n = (cell' = n>>2, gate q = n&3); MFMA m covers
// cells 4m..4m+3 of the wave's 16. After 4 MFMAs each lane holds exactly ONE
// (cell,gate) value (select its quad's MFMA) -> single unified activation for
// all 64 lanes (2 transcendentals), then 4 DPP quad-broadcasts gather i,f,g,o.
// Weights/bias pre-scaled by log2e (2*log2e for g-gate) -> exp2-native.
__global__ __launch_bounds__(512, 2) void lstm_mfma(
    const float* __restrict__ x,      // [T,B,I]
    const float* __restrict__ h0,     // [B,H]
    const float* __restrict__ c0,     // [B,H]
    const float* __restrict__ Wih,    // [4H,I]
    const float* __restrict__ Whh,    // [4H,H]
    const float* __restrict__ bih,    // [4H]
    const float* __restrict__ bhh,    // [4H]
    const float* __restrict__ fcW,    // [18,H]
    const float* __restrict__ fcb,    // [18]
    float* __restrict__ out,          // [T,B,18]
    float* __restrict__ hT,           // [B,H]
    float* __restrict__ cT)           // [B,H]
{
  const int b    = blockIdx.x;
  const int tid  = threadIdx.x;
  const int w    = tid >> 6;      // wave 0..7
  const int l    = tid & 63;
  const int n    = l & 15;        // tile col
  const int quad = l >> 4;        // k-chunk within frag / MFMA-select
  const int q4   = l & 3;         // gate type of this lane
  const int c4   = (l >> 2) & 3;  // cell-within-MFMA of this lane

  __shared__ __align__(16) _Float16 xs[CH][136];    // x chunk f16 (+pad)      8704 B
  __shared__ __align__(16) float    xgp[CH][XGS];   // x-gates f32            66048 B
  __shared__ __align__(16) _Float16 hist[CH][128];  // h ring / history        8192 B
  __shared__ __align__(16) uint32_t fcw[NC][66];    // head W f16 (+pad)       4752 B

  // ---- persistent weight B-frags (col map (c',q)): Whh + Wih, 128 VGPRs ----
  const float sc = (q4 == 2) ? TWO_LOG2E_F : LOG2E_F;
  f16x8 whh[4][4], wih[4][4];
  float biasv[4];
#pragma unroll
  for (int m = 0; m < 4; ++m){
    const int row = q4*128 + w*16 + 4*m + c4;
#pragma unroll
    for (int kt = 0; kt < 4; ++kt){
      whh[m][kt] = ldrow_f16s(Whh + (size_t)row*NH + kt*32 + quad*8, sc);
      wih[m][kt] = ldrow_f16s(Wih + (size_t)row*NI + kt*32 + quad*8, sc);
    }
    biasv[m] = (bih[row] + bhh[row]) * sc;
  }

  // ---- unified-activation per-lane constants ----
  const uint32_t smask = (q4 == 2) ? 0u : 0x80000000u;
  const float aK = (q4 == 2) ? 1.f : 0.f;
  const float sK = (q4 == 2) ? -2.f : 1.f;

  // ---- per-lane cell state (4 lanes per cell, redundant) ----
  const int mycell = w*16 + quad*4 + c4;
  float cst = c0[(size_t)b*NH + mycell];
  float hlast = 0.f;

  if (tid < 128) hist[CH-1][tid] = (_Float16)h0[(size_t)b*NH + tid];  // ring seed
#pragma unroll
  for (int r = 0; r < 3; ++r){
    int idx = tid + 512*r;                   // 18*64 = 1152 targets
    if (idx < NC*64){
      int j = idx >> 6, k = idx & 63;
      float2 f = ((const float2*)(fcW + (size_t)j*NH))[k];
      fcw[j][k] = pku(f.x, f.y);
    }
  }

  // ---- prefetch x chunk 0 into registers ----
  const int ttA = tid >> 5;                  // 0..15
  const int ttB = ttA + 16;                  // 16..31
  const int k4  = tid & 31;
  float4 xpA = ((const float4*)(x + ((size_t)ttA*NB + b)*NI))[k4];
  float4 xpB = ((const float4*)(x + ((size_t)ttB*NB + b)*NI))[k4];
  __syncthreads();

#pragma unroll 1
  for (int ck = 0; ck < NCHUNK; ++ck){
    const int t0 = ck*CH;

    // ---------- xs <- prefetched registers (f16) ----------
    {
      union { _Float16 h[4]; uint2 u2; } pa, pb;
      pa.h[0]=(_Float16)xpA.x; pa.h[1]=(_Float16)xpA.y;
      pa.h[2]=(_Float16)xpA.z; pa.h[3]=(_Float16)xpA.w;
      *(uint2*)&xs[ttA][4*k4] = pa.u2;
      pb.h[0]=(_Float16)xpB.x; pb.h[1]=(_Float16)xpB.y;
      pb.h[2]=(_Float16)xpB.z; pb.h[3]=(_Float16)xpB.w;
      *(uint2*)&xs[ttB][4*k4] = pb.u2;
    }
    barrier_lds();   // xs ready; also orders prev head's hist reads before new hist writes

    // ---------- x-GEMM: XG[32,512] = X @ Wih^T + bias (new (c',q) col map) ----------
    {
      f16x8 xa[2][4];                        // A-frags [mt][kt]
#pragma unroll
      for (int mt = 0; mt < 2; ++mt)
#pragma unroll
        for (int kt = 0; kt < 4; ++kt)
          xa[mt][kt] = *(const f16x8*)&xs[mt*16 + n][kt*32 + quad*8];

#pragma unroll
      for (int m = 0; m < 4; ++m){
#pragma unroll
        for (int mt = 0; mt < 2; ++mt){
          f32x4 acc = { biasv[m], biasv[m], biasv[m], biasv[m] };
#pragma unroll
          for (int kt = 0; kt < 4; ++kt)
            acc = __builtin_amdgcn_mfma_f32_16x16x32_f16(xa[mt][kt], wih[m][kt], acc, 0, 0, 0);
#pragma unroll
          for (int r = 0; r < 4; ++r)
            xgp[mt*16 + quad*4 + r][w*64 + n*4 + m] = acc[r];
        }
      }
    }

    // issue next chunk's x loads now; lgkm-only barriers keep them in flight
    if (ck + 1 < NCHUNK){
      const size_t t1 = (size_t)(t0 + CH);
      xpA = ((const float4*)(x + ((t1 + ttA)*NB + b)*NI))[k4];
      xpB = ((const float4*)(x + ((t1 + ttB)*NB + b)*NI))[k4];
    }
    barrier_lds();   // xgp ready

    // ---------- 32 recurrent steps ----------
#pragma unroll 4
    for (int tt = 0; tt < CH; ++tt){
      // lane's 4 seeds (m=0..3) contiguous: ONE b128
      f32x4 sgv = *(const f32x4*)&xgp[tt][w*64 + n*4];
      const int rp = (tt + CH - 1) & (CH - 1);   // previous h in the ring
      const _Float16* hprev = &hist[rp][0];
      f16x8 a0 = *(const f16x8*)&hprev[ 0 + quad*8];
      f16x8 a1 = *(const f16x8*)&hprev[32 + quad*8];
      f16x8 a2 = *(const f16x8*)&hprev[64 + quad*8];
      f16x8 a3 = *(const f16x8*)&hprev[96 + quad*8];
      float g0, g1, g2, g3;
      {
        f32x4 aA, aB;
        aA[0] = sgv[0];
        aA = __builtin_amdgcn_mfma_f32_16x16x32_f16(a0, whh[0][0], aA, 0, 0, 0);
        aA = __builtin_amdgcn_mfma_f32_16x16x32_f16(a1, whh[0][1], aA, 0, 0, 0);
        aB[0] = 0.f;
        aB = __builtin_amdgcn_mfma_f32_16x16x32_f16(a2, whh[0][2], aB, 0, 0, 0);
        aB = __builtin_amdgcn_mfma_f32_16x16x32_f16(a3, whh[0][3], aB, 0, 0, 0);
        g0 = aA[0] + aB[0];
      }
      {
        f32x4 aA, aB;
        aA[0] = sgv[1];
        aA = __builtin_amdgcn_mfma_f32_16x16x32_f16(a0, whh[1][0], aA, 0, 0, 0);
        aA = __builtin_amdgcn_mfma_f32_16x16x32_f16(a1, whh[1][1], aA, 0, 0, 0);
        aB[0] = 0.f;
        aB = __builtin_amdgcn_mfma_f32_16x16x32_f16(a2, whh[1][2], aB, 0, 0, 0);
        aB = __builtin_amdgcn_mfma_f32_16x16x32_f16(a3, whh[1][3], aB, 0, 0, 0);
        g1 = aA[0] + aB[0];
      }
      {
        f32x4 aA, aB;
        aA[0] = sgv[2];
        aA = __builtin_amdgcn_mfma_f32_16x16x32_f16(a0, whh[2][0], aA, 0, 0, 0);
        aA = __builtin_amdgcn_mfma_f32_16x16x32_f16(a1, whh[2][1], aA, 0, 0, 0);
        aB[0] = 0.f;
        aB = __builtin_amdgcn_mfma_f32_16x16x32_f16(a2, whh[2][2], aB, 0, 0, 0);
        aB = __builtin_amdgcn_mfma_f32_16x16x32_f16(a3, whh[2][3], aB, 0, 0, 0);
        g2 = aA[0] + aB[0];
      }
      {
        f32x4 aA, aB;
        aA[0] = sgv[3];
        aA = __builtin_amdgcn_mfma_f32_16x16x32_f16(a0, whh[3][0], aA, 0, 0, 0);
        aA = __builtin_amdgcn_mfma_f32_16x16x32_f16(a1, whh[3][1], aA, 0, 0, 0);
        aB[0] = 0.f;
        aB = __builtin_amdgcn_mfma_f32_16x16x32_f16(a2, whh[3][2], aB, 0, 0, 0);
        aB = __builtin_amdgcn_mfma_f32_16x16x32_f16(a3, whh[3][3], aB, 0, 0, 0);
        g3 = aA[0] + aB[0];
      }
      // select this lane's (cell,gate) value: MFMA index = quad
      const bool qlo = (quad & 1) != 0;
      const bool qhi = (quad & 2) != 0;
      float gsel = qhi ? (qlo ? g3 : g2) : (qlo ? g1 : g0);
      // unified activation (sigmoid for q in {0,1,3}, tanh for q==2), all lanes
      union { float f; uint32_t u; } gx; gx.f = gsel; gx.u ^= smask;
      float ev  = exp2x(gx.f);
      float rr  = fast_rcp(1.f + ev);
      float act = __builtin_fmaf(sK, rr, aK);
      // gather i,f,g,o of this cell from the 4 adjacent lanes (free DPP)
      float vi = qbcast<0x00>(act);
      float vf = qbcast<0x55>(act);
      float vg = qbcast<0xAA>(act);
      float vo = qbcast<0xFF>(act);
      cst = __builtin_fmaf(vf, cst, vi*vg);
      float e2 = exp2x(cst * TWO_LOG2E_F);
      float tc = __builtin_fmaf(-2.f, fast_rcp(1.f + e2), 1.f);
      float hv = vo * tc;
      hlast = hv;
      if (q4 == 0)                           // one writer per cell-group
        hist[tt][mycell] = (_Float16)hv;
      barrier_lds();
    }

    // ---------- fused head for this chunk (reads hist; next chunk-top
    // barriers order these reads before hist is rewritten) ----------
    {
      const int tt = tid >> 4;               // 0..31
      const int jb = tid & 15;
      const uint4* hb = (const uint4*)&hist[tt][0];
#pragma unroll
      for (int jj = 0; jj < 2; ++jj){
        const int j = jj*16 + jb;
        if (j < NC){
          const uint2* fw = (const uint2*)&fcw[j][0];
          float a0=0.f, a1=0.f, a2=0.f, a3=0.f;
#pragma unroll
          for (int q = 0; q < 4; ++q){
            uint4 v0 = hb[q], v1 = hb[4+q], v2 = hb[8+q], v3 = hb[12+q];
            uint2 f0a = fw[2*q],    f0b = fw[2*q+1];
            uint2 f1a = fw[8+2*q],  f1b = fw[8+2*q+1];
            uint2 f2a = fw[16+2*q], f2b = fw[16+2*q+1];
            uint2 f3a = fw[24+2*q], f3b = fw[24+2*q+1];
            a0 = dot2f(as_h2(f0a.x), as_h2(v0.x), a0);
            a1 = dot2f(as_h2(f1a.x), as_h2(v1.x), a1);
            a2 = dot2f(as_h2(f2a.x), as_h2(v2.x), a2);
            a3 = dot2f(as_h2(f3a.x), as_h2(v3.x), a3);
            a0 = dot2f(as_h2(f0a.y), as_h2(v0.y), a0);
            a1 = dot2f(as_h2(f1a.y), as_h2(v1.y), a1);
            a2 = dot2f(as_h2(f2a.y), as_h2(v2.y), a2);
            a3 = dot2f(as_h2(f3a.y), as_h2(v3.y), a3);
            a0 = dot2f(as_h2(f0b.x), as_h2(v0.z), a0);
            a1 = dot2f(as_h2(f1b.x), as_h2(v1.z), a1);
            a2 = dot2f(as_h2(f2b.x), as_h2(v2.z), a2);
            a3 = dot2f(as_h2(f3b.x), as_h2(v3.z), a3);
            a0 = dot2f(as_h2(f0b.y), as_h2(v0.w), a0);
            a1 = dot2f(as_h2(f1b.y), as_h2(v1.w), a1);
            a2 = dot2f(as_h2(f2b.y), as_h2(v2.w), a2);
            a3 = dot2f(as_h2(f3b.y), as_h2(v3.w), a3);
          }
          out[(size_t)(t0+tt)*NB*NC + (size_t)b*NC + j] =
              (a0+a1) + (a2+a3) + fcb[j];
        }
      }
    }
  }

  // ---------- final hT / cT (from registers, one writer per cell) ----------
  if (q4 == 0){
    hT[(size_t)b*NH + mycell] = hlast;
    cT[(size_t)b*NH + mycell] = cst;
  }
}

extern "C" void kernel_launch(void* const* d_in, const int* in_sizes, int n_in,
                              void* d_out, int out_size, void* d_ws, size_t ws_size,
                              hipStream_t stream) {
  (void)in_sizes; (void)n_in; (void)d_ws; (void)ws_size; (void)out_size;
  const float* x   = (const float*)d_in[0];
  const float* h0  = (const float*)d_in[1];
  const float* c0  = (const float*)d_in[2];
  const float* Wih = (const float*)d_in[3];
  const float* Whh = (const float*)d_in[4];
  const float* bih = (const float*)d_in[5];
  const float* bhh = (const float*)d_in[6];
  const float* fcW = (const float*)d_in[7];
  const float* fcb = (const float*)d_in[8];
  float* out = (float*)d_out;
  float* hT  = out + (size_t)TSTEPS*NB*NC;   // 4,718,592
  float* cT  = hT + (size_t)NB*NH;           // +32,768
  hipLaunchKernelGGL(lstm_mfma, dim3(NB), dim3(512), 0, stream,
                     x, h0, c0, Wih, Whh, bih, bhh, fcW, fcb, out, hT, cT);
}